// Round 2
// baseline (469.482 us; speedup 1.0000x reference)
//
#include <hip/hip_runtime.h>
#include <hip/hip_bf16.h>

// out = (Q K^T) V * scale, softmax discarded => associativity:
//   out_i = Q_i @ (K_i^T @ V_i) * scale over 32 blocks of 2048 flat rows of
//   the (65536,64) view of the (4096,1024) projections.
// R12: single resident megakernel (768 blocks, 3/CU guaranteed by
// __launch_bounds__(256,3) + 32KB LDS) running the proven R10 phase bodies
// back-to-back with device-scope grid barriers:
//   phase1 QKV GEMM (768 tiles) -> phase2 kT (256 blk) -> phase3 reduce
//   (512 blk) -> phase4 qT (512 blk). Removes 3 launch gaps + drains.

#define E_DIM 1024
#define N_ROWS 4096

typedef __attribute__((ext_vector_type(8))) short bf16x8;
typedef __attribute__((ext_vector_type(4))) float f32x4;

// ---- ws layout ----
// shorts: QB 0  KB 4194304  VB 8388608  XB 12582912  WB 16777216
//         TB 24117248 (bf16 Tt[32][64][64])
// floats: P 9961472 (32 blk x 8 chunks x 4096, [d][e])   BAR 11010048
#define QB_U 0
#define KB_U 4194304
#define VB_U 8388608
#define XB_U 12582912
#define WB_U 16777216
#define P_F  9961472
#define BAR_F 11010048
#define TB_U 24117248

#define NBLK 768u

__device__ __forceinline__ unsigned short f2b(float f) {
    union { float f; unsigned int i; } c; c.f = f;
    unsigned int r = c.i + 0x7FFFu + ((c.i >> 16) & 1u);   // RNE (finite data)
    return (unsigned short)(r >> 16);
}

typedef __attribute__((address_space(1))) const void* gptr_t;
typedef __attribute__((address_space(3))) void* lptr_t;
__device__ __forceinline__ void gl_lds16(const void* g, void* l) {
    __builtin_amdgcn_global_load_lds((gptr_t)g, (lptr_t)l, 16, 0, 0);
}

// swizzled index into a [row][64] LDS tile (8 slots of 8 elems per row)
__device__ __forceinline__ int sw_idx(int row, int r) {
    return row * 64 + (((((r) >> 3) & 7) ^ (row & 7)) << 3) + (r & 7);
}

// device-scope grid barrier: monotone counter, all NBLK blocks arrive.
__device__ __forceinline__ void gsync(unsigned* bar, unsigned target) {
    __syncthreads();
    if (threadIdx.x == 0) {
        __threadfence();   // release: agent-scope (L2 writeback on gfx950)
        __hip_atomic_fetch_add(bar, 1u, __ATOMIC_RELEASE, __HIP_MEMORY_SCOPE_AGENT);
        while (__hip_atomic_load(bar, __ATOMIC_ACQUIRE, __HIP_MEMORY_SCOPE_AGENT) < target)
            __builtin_amdgcn_s_sleep(2);
        __threadfence();   // acquire: invalidate stale L1/L2
    }
    __syncthreads();
}

// ---------------------------------------------------------------------------
// Kernel 0: fp32 -> bf16 convert: x (4 MB-segs) + Wq/Wk/Wv. Also zeroes bar.
// ---------------------------------------------------------------------------
__global__ __launch_bounds__(256) void cvt_bf16(
    const float* __restrict__ x,  const float* __restrict__ wq,
    const float* __restrict__ wk, const float* __restrict__ wv,
    unsigned short* __restrict__ dst0, unsigned* __restrict__ bar)
{
    if (blockIdx.x == 0 && blockIdx.y == 0 && threadIdx.x == 0) *bar = 0u;
    const int seg = blockIdx.y;
    const float* __restrict__ src;
    unsigned short* __restrict__ dst;
    if (seg < 4) { src = x + (size_t)seg * 1048576; dst = dst0 + (size_t)seg * 1048576; }
    else {
        src = (seg == 4) ? wq : (seg == 5) ? wk : wv;
        dst = dst0 + 4194304 + (size_t)(seg - 4) * 1048576;
    }
    const int i = blockIdx.x * 256 + threadIdx.x;   // 0..131071
    const float4 a = *(const float4*)(src + (size_t)i * 8);
    const float4 b = *(const float4*)(src + (size_t)i * 8 + 4);
    uint4 o;
    o.x = (unsigned)f2b(a.x) | ((unsigned)f2b(a.y) << 16);
    o.y = (unsigned)f2b(a.z) | ((unsigned)f2b(a.w) << 16);
    o.z = (unsigned)f2b(b.x) | ((unsigned)f2b(b.y) << 16);
    o.w = (unsigned)f2b(b.z) | ((unsigned)f2b(b.w) << 16);
    *(uint4*)(dst + (size_t)i * 8) = o;
}

// ---------------------------------------------------------------------------
// Megakernel: 768 blocks x 256 threads, 3 blocks/CU resident (32KB LDS,
// launch_bounds(256,3)). Phases separated by gsync.
// ---------------------------------------------------------------------------
__global__ __launch_bounds__(256, 3) void mega(
    const unsigned short* __restrict__ Xb,
    const unsigned short* __restrict__ Wb,
    const float* __restrict__ bq, const float* __restrict__ bk,
    const float* __restrict__ bv,
    unsigned short* __restrict__ qkv,
    float* __restrict__ P,
    unsigned short* __restrict__ TB,
    float* __restrict__ out,
    unsigned* __restrict__ bar)
{
    __shared__ __align__(16) unsigned short S[16384];   // 32 KB, reused per phase

    const int b    = blockIdx.x;
    const int tid  = threadIdx.x;
    const int w    = tid >> 6;
    const int lane = tid & 63;
    const int quad = lane >> 4;
    const int fm   = lane & 15;
    const int sw8  = fm & 7;
    const int rbase = quad * 4;

    // ================= phase 1: QKV GEMM (R10 qkv_gemm body) =================
    {
        const int which = b >> 8;                       // 0=Q 1=K 2=V
        const unsigned short* __restrict__ W = Wb + (size_t)which * (1024 * 1024);
        const float* __restrict__ bias = (which == 0) ? bq : (which == 1) ? bk : bv;
        unsigned short* __restrict__ Y = qkv + (size_t)which * ((size_t)N_ROWS * E_DIM);
        const int m0 = (b & 31) * 128;
        const int n0 = ((b >> 5) & 7) * 128;
        const int wm = (w >> 1) * 64;
        const int wn = (w & 1) * 64;
        unsigned short* Als = S;          // [128][64] swizzled
        unsigned short* Bls = S + 8192;   // [128][64] swizzled

        f32x4 acc[4][4];
        #pragma unroll
        for (int i = 0; i < 4; ++i)
            #pragma unroll
            for (int j = 0; j < 4; ++j)
                acc[i][j] = f32x4{0.f, 0.f, 0.f, 0.f};

        const int srow = lane >> 3;
        const int skc  = ((lane & 7) ^ (lane >> 3)) * 8;

        for (int k0 = 0; k0 < E_DIM; k0 += 64) {
            #pragma unroll
            for (int c = 0; c < 4; ++c) {
                const int r = w * 32 + c * 8;
                gl_lds16((const void*)(Xb + (size_t)(m0 + r + srow) * E_DIM + k0 + skc),
                         (void*)((char*)Als + r * 128 + lane * 16));
                gl_lds16((const void*)(W + (size_t)(n0 + r + srow) * E_DIM + k0 + skc),
                         (void*)((char*)Bls + r * 128 + lane * 16));
            }
            __syncthreads();

            #pragma unroll
            for (int kk = 0; kk < 2; ++kk) {
                const int slot = ((kk * 4 + quad) ^ sw8) * 8;
                bf16x8 af[4], bf[4];
                #pragma unroll
                for (int t = 0; t < 4; ++t) {
                    af[t] = *(const bf16x8*)(Als + (wm + t * 16 + fm) * 64 + slot);
                    bf[t] = *(const bf16x8*)(Bls + (wn + t * 16 + fm) * 64 + slot);
                }
                #pragma unroll
                for (int rt = 0; rt < 4; ++rt)
                    #pragma unroll
                    for (int ct = 0; ct < 4; ++ct)
                        acc[rt][ct] = __builtin_amdgcn_mfma_f32_16x16x32_bf16(
                            af[rt], bf[ct], acc[rt][ct], 0, 0, 0);
            }
            __syncthreads();
        }

        float bcol[4];
        #pragma unroll
        for (int ct = 0; ct < 4; ++ct) bcol[ct] = bias[n0 + wn + ct * 16 + fm];

        #pragma unroll
        for (int rt = 0; rt < 4; ++rt) {
            #pragma unroll
            for (int ct = 0; ct < 4; ++ct) {
                #pragma unroll
                for (int r = 0; r < 4; ++r) {
                    const int row = m0 + wm + rt * 16 + rbase + r;
                    const int col = n0 + wn + ct * 16 + fm;
                    Y[(size_t)row * E_DIM + col] = f2b(acc[rt][ct][r] + bcol[ct]);
                }
            }
        }
    }

    gsync(bar, NBLK);

    // ================= phase 2: kT (R10 kT_mfma body, blocks 0..255) ========
    if (b < 256) {
        unsigned short* Kt = S;          // [e][r] swizzled, 8 KB
        unsigned short* Vt = S + 4096;   // [d][r] swizzled, 8 KB
        const size_t base = (size_t)(b >> 3) * (2048 * 64) + (size_t)(b & 7) * (256 * 64);
        const unsigned short* __restrict__ Kb = qkv + KB_U + base;
        const unsigned short* __restrict__ Vb = qkv + VB_U + base;
        float* __restrict__ Pout = P + (size_t)b * 4096;
        const int eo = w * 16;

        f32x4 acc[4];
        #pragma unroll
        for (int nt = 0; nt < 4; ++nt) acc[nt] = f32x4{0.f, 0.f, 0.f, 0.f};

        for (int rb = 0; rb < 256; rb += 64) {
            union { uint4 u; unsigned short s[8]; } k0, k1, v0, v1;
            const size_t ga = (size_t)(rb + lane) * 64 + eo;
            k0.u = *(const uint4*)(Kb + ga);
            k1.u = *(const uint4*)(Kb + ga + 8);
            v0.u = *(const uint4*)(Vb + ga);
            v1.u = *(const uint4*)(Vb + ga + 8);
            __syncthreads();
            #pragma unroll
            for (int j = 0; j < 8; ++j) {
                Kt[sw_idx(eo + j, lane)]     = k0.s[j];
                Kt[sw_idx(eo + 8 + j, lane)] = k1.s[j];
                Vt[sw_idx(eo + j, lane)]     = v0.s[j];
                Vt[sw_idx(eo + 8 + j, lane)] = v1.s[j];
            }
            __syncthreads();
            #pragma unroll
            for (int kk = 0; kk < 2; ++kk) {
                const int slot = ((kk * 4 + quad) ^ sw8) << 3;
                const bf16x8 af = *(const bf16x8*)(Vt + (w * 16 + fm) * 64 + slot);
                #pragma unroll
                for (int nt = 0; nt < 4; ++nt) {
                    const bf16x8 bf = *(const bf16x8*)(Kt + (nt * 16 + fm) * 64 + slot);
                    acc[nt] = __builtin_amdgcn_mfma_f32_16x16x32_bf16(af, bf, acc[nt], 0, 0, 0);
                }
            }
        }

        #pragma unroll
        for (int nt = 0; nt < 4; ++nt)
            #pragma unroll
            for (int r = 0; r < 4; ++r)
                Pout[(size_t)(w * 16 + rbase + r) * 64 + nt * 16 + fm] = acc[nt][r];
    }

    gsync(bar, 2u * NBLK);

    // ================= phase 3: reduce 8 partials -> TB bf16 (blocks 0..511) =
    if (b < 512) {
        const int idx = b * 256 + tid;    // 0..131071
        const int i   = idx >> 12;
        const int off = idx & 4095;       // d*64 + e
        const float* p = P + (size_t)i * 8 * 4096 + off;
        float s = 0.0f;
        #pragma unroll
        for (int c = 0; c < 8; ++c) s += p[(size_t)c * 4096];
        TB[(size_t)i * 4096 + off] = f2b(s);
    }

    gsync(bar, 3u * NBLK);

    // ================= phase 4: qT (R10 qT_mfma body, blocks 0..511) ========
    if (b < 512) {
        unsigned short* Als = S;          // [128][64] swizzled Q rows, 16 KB
        unsigned short* Bls = S + 8192;   // [64][64]  swizzled Tt rows, 8 KB
        const int r0 = b * 128;
        const int i  = b >> 4;
        const unsigned short* __restrict__ Qb = qkv + QB_U + (size_t)r0 * 64;
        const unsigned short* __restrict__ Tb = TB + (size_t)i * 4096;

        const int soff = (lane >> 3) * 64 + (((lane & 7) ^ (lane >> 3)) << 3);
        #pragma unroll
        for (int c = 0; c < 4; ++c)
            gl_lds16((const void*)(Qb + (w * 4 + c) * 512 + soff),
                     (void*)((char*)Als + (w * 4 + c) * 1024));
        #pragma unroll
        for (int c = 0; c < 2; ++c)
            gl_lds16((const void*)(Tb + (w * 2 + c) * 512 + soff),
                     (void*)((char*)Bls + (w * 2 + c) * 1024));
        __syncthreads();

        bf16x8 af[2][2], bf[4][2];
        #pragma unroll
        for (int mt = 0; mt < 2; ++mt)
            #pragma unroll
            for (int kk = 0; kk < 2; ++kk)
                af[mt][kk] = *(const bf16x8*)(Als + (w * 32 + mt * 16 + fm) * 64
                                              + (((kk * 4 + quad) ^ sw8) << 3));
        #pragma unroll
        for (int nt = 0; nt < 4; ++nt)
            #pragma unroll
            for (int kk = 0; kk < 2; ++kk)
                bf[nt][kk] = *(const bf16x8*)(Bls + (nt * 16 + fm) * 64
                                              + (((kk * 4 + quad) ^ sw8) << 3));

        f32x4 acc[2][4];
        #pragma unroll
        for (int mt = 0; mt < 2; ++mt)
            #pragma unroll
            for (int nt = 0; nt < 4; ++nt)
                acc[mt][nt] = f32x4{0.f, 0.f, 0.f, 0.f};

        #pragma unroll
        for (int kk = 0; kk < 2; ++kk)
            #pragma unroll
            for (int mt = 0; mt < 2; ++mt)
                #pragma unroll
                for (int nt = 0; nt < 4; ++nt)
                    acc[mt][nt] = __builtin_amdgcn_mfma_f32_16x16x32_bf16(
                        af[mt][kk], bf[nt][kk], acc[mt][nt], 0, 0, 0);

        #pragma unroll
        for (int mt = 0; mt < 2; ++mt) {
            #pragma unroll
            for (int nt = 0; nt < 4; ++nt) {
                #pragma unroll
                for (int r = 0; r < 4; ++r) {
                    const int row = r0 + w * 32 + mt * 16 + rbase + r;
                    const int col = nt * 16 + fm;
                    out[(size_t)row * 64 + col] = 0.125f * acc[mt][nt][r];
                }
            }
        }
    }
}

extern "C" void kernel_launch(void* const* d_in, const int* in_sizes, int n_in,
                              void* d_out, int out_size, void* d_ws, size_t ws_size,
                              hipStream_t stream)
{
    const float* x  = (const float*)d_in[0];
    const float* Wq = (const float*)d_in[1];
    const float* bq = (const float*)d_in[2];
    const float* Wk = (const float*)d_in[3];
    const float* bk = (const float*)d_in[4];
    const float* Wv = (const float*)d_in[5];
    const float* bv = (const float*)d_in[6];
    float* wsf = (float*)d_ws;
    unsigned short* wsu = (unsigned short*)d_ws;
    float* out = (float*)d_out;
    unsigned* bar = (unsigned*)(wsf + BAR_F);

    dim3 gCvt(512, 7);
    cvt_bf16<<<gCvt, 256, 0, stream>>>(x, Wq, Wk, Wv, wsu + XB_U, bar);

    mega<<<dim3(NBLK), 256, 0, stream>>>(wsu + XB_U, wsu + WB_U,
                                         bq, bk, bv,
                                         wsu, wsf + P_F, wsu + TB_U,
                                         out, bar);
}

// Round 4
// 132.344 us; speedup vs baseline: 3.5475x; 3.5475x over previous
//
#include <hip/hip_runtime.h>
#include <hip/hip_bf16.h>

// out = (Q K^T) V * scale, softmax discarded => associativity:
//   out_i = Q_i @ (K_i^T @ V_i) * scale over 32 blocks of 2048 flat rows of
//   the (65536,64) view of the (4096,1024) projections.
// R14: back to the proven multi-kernel structure (R12/R13 grid-sync dead on
// this harness). 4 kernels: cvt -> qkv_gemm (768) -> kT (512 blk, 128-row
// chunks, 2x parallelism) -> qT_fused (512 blk: redundant P-reduce prologue
// [R11-verified] + K=64 mini-GEMM). XCD-aligned mapping: kT block x=i writes
// P[i] on XCD i%8; qT_fused i=(b&7)+((b>>3)&3)*8 reads it on the same XCD.

#define E_DIM 1024
#define N_ROWS 4096

typedef __attribute__((ext_vector_type(8))) short bf16x8;
typedef __attribute__((ext_vector_type(4))) float f32x4;

// ---- ws layout ----
// shorts: QB 0  KB 4194304  VB 8388608  XB 12582912  WB 16777216
// floats: P 9961472 (32 blk x 16 chunks x 4096, [d][e]) = 8 MB
#define QB_U 0
#define KB_U 4194304
#define VB_U 8388608
#define XB_U 12582912
#define WB_U 16777216
#define P_F  9961472

__device__ __forceinline__ unsigned short f2b(float f) {
    union { float f; unsigned int i; } c; c.f = f;
    unsigned int r = c.i + 0x7FFFu + ((c.i >> 16) & 1u);   // RNE (finite data)
    return (unsigned short)(r >> 16);
}

__device__ __forceinline__ uint4 pack8(const f32x4 a, const f32x4 b) {
    uint4 o;
    o.x = (unsigned)f2b(a[0]) | ((unsigned)f2b(a[1]) << 16);
    o.y = (unsigned)f2b(a[2]) | ((unsigned)f2b(a[3]) << 16);
    o.z = (unsigned)f2b(b[0]) | ((unsigned)f2b(b[1]) << 16);
    o.w = (unsigned)f2b(b[2]) | ((unsigned)f2b(b[3]) << 16);
    return o;
}

typedef __attribute__((address_space(1))) const void* gptr_t;
typedef __attribute__((address_space(3))) void* lptr_t;
__device__ __forceinline__ void gl_lds16(const void* g, void* l) {
    __builtin_amdgcn_global_load_lds((gptr_t)g, (lptr_t)l, 16, 0, 0);
}

// swizzled index into a [row][64] LDS tile (8 slots of 8 elems per row)
__device__ __forceinline__ int sw_idx(int row, int r) {
    return row * 64 + (((((r) >> 3) & 7) ^ (row & 7)) << 3) + (r & 7);
}

// ---------------------------------------------------------------------------
// Kernel 0: fp32 -> bf16 convert: x (4 MB-segs) + Wq/Wk/Wv.
// ---------------------------------------------------------------------------
__global__ __launch_bounds__(256) void cvt_bf16(
    const float* __restrict__ x,  const float* __restrict__ wq,
    const float* __restrict__ wk, const float* __restrict__ wv,
    unsigned short* __restrict__ dst0)
{
    const int seg = blockIdx.y;
    const float* __restrict__ src;
    unsigned short* __restrict__ dst;
    if (seg < 4) { src = x + (size_t)seg * 1048576; dst = dst0 + (size_t)seg * 1048576; }
    else {
        src = (seg == 4) ? wq : (seg == 5) ? wk : wv;
        dst = dst0 + 4194304 + (size_t)(seg - 4) * 1048576;
    }
    const int i = blockIdx.x * 256 + threadIdx.x;   // 0..131071
    const float4 a = *(const float4*)(src + (size_t)i * 8);
    const float4 b = *(const float4*)(src + (size_t)i * 8 + 4);
    uint4 o;
    o.x = (unsigned)f2b(a.x) | ((unsigned)f2b(a.y) << 16);
    o.y = (unsigned)f2b(a.z) | ((unsigned)f2b(a.w) << 16);
    o.z = (unsigned)f2b(b.x) | ((unsigned)f2b(b.y) << 16);
    o.w = (unsigned)f2b(b.z) | ((unsigned)f2b(b.w) << 16);
    *(uint4*)(dst + (size_t)i * 8) = o;
}

// ---------------------------------------------------------------------------
// Kernel A: Y(bf16) = Xb @ Wb^T + bias (blockIdx.z selects weight). R10 body.
// 128x128 tile, BK=64 (32 KB LDS), global_load_lds x16, 16x16x32 bf16 MFMA,
// fp32 acc, XOR-swizzled LDS.
// ---------------------------------------------------------------------------
__global__ __launch_bounds__(256, 3) void qkv_gemm_mfma(
    const unsigned short* __restrict__ Xb,
    const unsigned short* __restrict__ Wb,
    const float* __restrict__ bq, const float* __restrict__ bk,
    const float* __restrict__ bv,
    unsigned short* __restrict__ qkv)
{
    const int which = blockIdx.z;
    const unsigned short* __restrict__ W = Wb + (size_t)which * (1024 * 1024);
    const float* __restrict__ bias = (which == 0) ? bq : (which == 1) ? bk : bv;
    unsigned short* __restrict__ Y = qkv + (size_t)which * ((size_t)N_ROWS * E_DIM);

    __shared__ __align__(16) unsigned short Als[128 * 64];  // 16 KB
    __shared__ __align__(16) unsigned short Bls[128 * 64];  // 16 KB

    const int tid  = threadIdx.x;
    const int w    = tid >> 6;
    const int lane = tid & 63;
    const int m0 = blockIdx.x * 128;
    const int n0 = blockIdx.y * 128;
    const int wm = (w >> 1) * 64;
    const int wn = (w & 1) * 64;

    f32x4 acc[4][4];
    #pragma unroll
    for (int i = 0; i < 4; ++i)
        #pragma unroll
        for (int j = 0; j < 4; ++j)
            acc[i][j] = f32x4{0.f, 0.f, 0.f, 0.f};

    const int srow = lane >> 3;                       // 0..7
    const int skc  = ((lane & 7) ^ (lane >> 3)) * 8;  // swizzled global chunk
    const int quad = lane >> 4;
    const int fm   = lane & 15;
    const int sw8  = fm & 7;

    for (int k0 = 0; k0 < E_DIM; k0 += 64) {
        #pragma unroll
        for (int c = 0; c < 4; ++c) {
            const int r = w * 32 + c * 8;
            gl_lds16((const void*)(Xb + (size_t)(m0 + r + srow) * E_DIM + k0 + skc),
                     (void*)((char*)Als + r * 128 + lane * 16));
            gl_lds16((const void*)(W + (size_t)(n0 + r + srow) * E_DIM + k0 + skc),
                     (void*)((char*)Bls + r * 128 + lane * 16));
        }
        __syncthreads();

        #pragma unroll
        for (int kk = 0; kk < 2; ++kk) {
            const int slot = ((kk * 4 + quad) ^ sw8) * 8;
            bf16x8 af[4], bf[4];
            #pragma unroll
            for (int t = 0; t < 4; ++t) {
                af[t] = *(const bf16x8*)(Als + (wm + t * 16 + fm) * 64 + slot);
                bf[t] = *(const bf16x8*)(Bls + (wn + t * 16 + fm) * 64 + slot);
            }
            #pragma unroll
            for (int rt = 0; rt < 4; ++rt)
                #pragma unroll
                for (int ct = 0; ct < 4; ++ct)
                    acc[rt][ct] = __builtin_amdgcn_mfma_f32_16x16x32_bf16(
                        af[rt], bf[ct], acc[rt][ct], 0, 0, 0);
        }
        __syncthreads();
    }

    float bcol[4];
    #pragma unroll
    for (int ct = 0; ct < 4; ++ct) bcol[ct] = bias[n0 + wn + ct * 16 + fm];

    const int rbase = (lane >> 4) * 4;
    #pragma unroll
    for (int rt = 0; rt < 4; ++rt) {
        #pragma unroll
        for (int ct = 0; ct < 4; ++ct) {
            #pragma unroll
            for (int r = 0; r < 4; ++r) {
                const int row = m0 + wm + rt * 16 + rbase + r;
                const int col = n0 + wn + ct * 16 + fm;
                Y[(size_t)row * E_DIM + col] = f2b(acc[rt][ct][r] + bcol[ct]);
            }
        }
    }
}

// ---------------------------------------------------------------------------
// Kernel B: kT via MFMA. Block (i=bx, c=by): 128-row chunk of attn block i.
//   Ppart[d][e] = sum_{r in chunk} V[r][d] * K[r][e]
// 512 blocks (2/CU) for 2x parallelism vs R10's 256. Block x=i lands on
// XCD i%8 (round-robin dispatch), so P[i] stays in that XCD's L2.
// ---------------------------------------------------------------------------
__global__ __launch_bounds__(256) void kT_mfma(
    const unsigned short* __restrict__ qkv, float* __restrict__ P)
{
    const size_t base = (size_t)blockIdx.x * (2048 * 64) + (size_t)blockIdx.y * (128 * 64);
    const unsigned short* __restrict__ Kb = qkv + KB_U + base;
    const unsigned short* __restrict__ Vb = qkv + VB_U + base;
    float* __restrict__ Pout = P + ((size_t)blockIdx.x * 16 + blockIdx.y) * 4096;

    __shared__ __align__(16) unsigned short Kt[64 * 64];  // [e][r] swizzled
    __shared__ __align__(16) unsigned short Vt[64 * 64];  // [d][r] swizzled

    const int tid  = threadIdx.x;
    const int w    = tid >> 6;
    const int lane = tid & 63;
    const int eo   = w * 16;
    const int quad = lane >> 4;
    const int fm   = lane & 15;
    const int sw8  = fm & 7;

    f32x4 acc[4];
    #pragma unroll
    for (int nt = 0; nt < 4; ++nt) acc[nt] = f32x4{0.f, 0.f, 0.f, 0.f};

    for (int rb = 0; rb < 128; rb += 64) {
        union { uint4 u; unsigned short s[8]; } k0, k1, v0, v1;
        const size_t ga = (size_t)(rb + lane) * 64 + eo;
        k0.u = *(const uint4*)(Kb + ga);
        k1.u = *(const uint4*)(Kb + ga + 8);
        v0.u = *(const uint4*)(Vb + ga);
        v1.u = *(const uint4*)(Vb + ga + 8);
        __syncthreads();
        #pragma unroll
        for (int j = 0; j < 8; ++j) {
            Kt[sw_idx(eo + j, lane)]     = k0.s[j];
            Kt[sw_idx(eo + 8 + j, lane)] = k1.s[j];
            Vt[sw_idx(eo + j, lane)]     = v0.s[j];
            Vt[sw_idx(eo + 8 + j, lane)] = v1.s[j];
        }
        __syncthreads();
        #pragma unroll
        for (int kk = 0; kk < 2; ++kk) {
            const int slot = ((kk * 4 + quad) ^ sw8) << 3;
            const bf16x8 af = *(const bf16x8*)(Vt + (w * 16 + fm) * 64 + slot);
            #pragma unroll
            for (int nt = 0; nt < 4; ++nt) {
                const bf16x8 bf = *(const bf16x8*)(Kt + (nt * 16 + fm) * 64 + slot);
                acc[nt] = __builtin_amdgcn_mfma_f32_16x16x32_bf16(af, bf, acc[nt], 0, 0, 0);
            }
        }
    }

    const int rbase = (lane >> 4) * 4;
    #pragma unroll
    for (int nt = 0; nt < 4; ++nt)
        #pragma unroll
        for (int r = 0; r < 4; ++r)
            Pout[(size_t)(w * 16 + rbase + r) * 64 + nt * 16 + fm] = acc[nt][r];
}

// ---------------------------------------------------------------------------
// Kernel C (fused): per block b: i = (b&7) + ((b>>3)&3)*8 (same XCD as the
// kT blocks that wrote P[i]), sub = b>>5. Redundant reduce of P[i]'s 16
// chunks -> Tls bf16 swizzled (R11-verified), Q tile staged async under it,
// then out = 0.125 * Qflat @ T^T (K=64 MFMA mini-GEMM, R10 body).
// ---------------------------------------------------------------------------
__global__ __launch_bounds__(256, 2) void qT_fused(
    const unsigned short* __restrict__ qkv,
    const float* __restrict__ P,
    float* __restrict__ out)
{
    __shared__ __align__(16) unsigned short Als[128 * 64];  // 16 KB: Q rows
    __shared__ __align__(16) unsigned short Tls[64 * 64];   //  8 KB: T[d][e]

    const int b    = blockIdx.x;            // 0..511
    const int i    = (b & 7) + ((b >> 3) & 3) * 8;   // attn block, XCD-aligned
    const int sub  = b >> 5;                          // 0..15
    const int r0   = (i * 16 + sub) * 128;            // flat Q row base
    const int tid  = threadIdx.x;
    const int w    = tid >> 6;
    const int lane = tid & 63;
    const int quad = lane >> 4;
    const int fm   = lane & 15;
    const int sw8  = fm & 7;

    const unsigned short* __restrict__ Qb = qkv + QB_U + (size_t)r0 * 64;

    // issue Q staging first (async via vmcnt; hides under the P reduce)
    const int soff = (lane >> 3) * 64 + (((lane & 7) ^ (lane >> 3)) << 3);
    #pragma unroll
    for (int c = 0; c < 4; ++c)
        gl_lds16((const void*)(Qb + (w * 4 + c) * 512 + soff),
                 (void*)((char*)Als + (w * 4 + c) * 1024));

    // redundant per-block reduce of P[i] (16 chunks) -> Tls bf16 swizzled
    {
        const int d  = tid >> 2;                       // 0..63
        const int e0 = (tid & 3) << 4;                 // 0,16,32,48
        const float* p = P + (size_t)i * 65536 + (size_t)d * 64 + e0;
        f32x4 s0{0.f,0.f,0.f,0.f}, s1{0.f,0.f,0.f,0.f};
        f32x4 s2{0.f,0.f,0.f,0.f}, s3{0.f,0.f,0.f,0.f};
        #pragma unroll
        for (int c = 0; c < 16; ++c) {
            s0 += *(const f32x4*)(p + (size_t)c * 4096);
            s1 += *(const f32x4*)(p + (size_t)c * 4096 + 4);
            s2 += *(const f32x4*)(p + (size_t)c * 4096 + 8);
            s3 += *(const f32x4*)(p + (size_t)c * 4096 + 12);
        }
        const int c0 = e0 >> 3;                        // even slot index
        *(uint4*)(Tls + d * 64 + ((c0 ^ (d & 7)) << 3))       = pack8(s0, s1);
        *(uint4*)(Tls + d * 64 + (((c0 + 1) ^ (d & 7)) << 3)) = pack8(s2, s3);
    }
    __syncthreads();   // drains gl_lds16 (vmcnt) + orders Tls writes

    // qT mini-GEMM (R10 body; B-fragments from Tls)
    bf16x8 af[2][2], bf[4][2];
    #pragma unroll
    for (int mt = 0; mt < 2; ++mt)
        #pragma unroll
        for (int kk = 0; kk < 2; ++kk)
            af[mt][kk] = *(const bf16x8*)(Als + (w * 32 + mt * 16 + fm) * 64
                                          + (((kk * 4 + quad) ^ sw8) << 3));
    #pragma unroll
    for (int nt = 0; nt < 4; ++nt)
        #pragma unroll
        for (int kk = 0; kk < 2; ++kk)
            bf[nt][kk] = *(const bf16x8*)(Tls + (nt * 16 + fm) * 64
                                          + (((kk * 4 + quad) ^ sw8) << 3));

    f32x4 acc[2][4];
    #pragma unroll
    for (int mt = 0; mt < 2; ++mt)
        #pragma unroll
        for (int nt = 0; nt < 4; ++nt)
            acc[mt][nt] = f32x4{0.f, 0.f, 0.f, 0.f};

    #pragma unroll
    for (int kk = 0; kk < 2; ++kk)
        #pragma unroll
        for (int mt = 0; mt < 2; ++mt)
            #pragma unroll
            for (int nt = 0; nt < 4; ++nt)
                acc[mt][nt] = __builtin_amdgcn_mfma_f32_16x16x32_bf16(
                    af[mt][kk], bf[nt][kk], acc[mt][nt], 0, 0, 0);

    const int rbase = (lane >> 4) * 4;
    #pragma unroll
    for (int mt = 0; mt < 2; ++mt) {
        #pragma unroll
        for (int nt = 0; nt < 4; ++nt) {
            #pragma unroll
            for (int r = 0; r < 4; ++r) {
                const int row = r0 + w * 32 + mt * 16 + rbase + r;
                const int col = nt * 16 + fm;
                out[(size_t)row * 64 + col] = 0.125f * acc[mt][nt][r];
            }
        }
    }
}

extern "C" void kernel_launch(void* const* d_in, const int* in_sizes, int n_in,
                              void* d_out, int out_size, void* d_ws, size_t ws_size,
                              hipStream_t stream)
{
    const float* x  = (const float*)d_in[0];
    const float* Wq = (const float*)d_in[1];
    const float* bq = (const float*)d_in[2];
    const float* Wk = (const float*)d_in[3];
    const float* bk = (const float*)d_in[4];
    const float* Wv = (const float*)d_in[5];
    const float* bv = (const float*)d_in[6];
    float* wsf = (float*)d_ws;
    unsigned short* wsu = (unsigned short*)d_ws;
    float* out = (float*)d_out;

    dim3 gCvt(512, 7);
    cvt_bf16<<<gCvt, 256, 0, stream>>>(x, Wq, Wk, Wv, wsu + XB_U);

    dim3 gA(N_ROWS / 128, E_DIM / 128, 3);   // 32 x 8 x 3
    qkv_gemm_mfma<<<gA, 256, 0, stream>>>(wsu + XB_U, wsu + WB_U,
                                          bq, bk, bv, wsu);

    dim3 gB(32, 16);                         // 512 blocks, 128-row chunks
    kT_mfma<<<gB, 256, 0, stream>>>(wsu, wsf + P_F);

    qT_fused<<<512, 256, 0, stream>>>(wsu, wsf + P_F, out);
}